// Round 13
// baseline (2409.600 us; speedup 1.0000x reference)
//
#include <hip/hip_runtime.h>
#include <hip/hip_bf16.h>

typedef _Float16 f16;
typedef _Float16 f16x2 __attribute__((ext_vector_type(2)));
typedef _Float16 f16x4 __attribute__((ext_vector_type(4)));
typedef _Float16 f16x8 __attribute__((ext_vector_type(8)));
typedef float f32x4 __attribute__((ext_vector_type(4)));

#define BATCH 128
#define SEQ   1024
#define IND   256
#define HID   512

#if defined(__has_builtin)
#if __has_builtin(__builtin_amdgcn_fdot2)
#define HAVE_FDOT2 1
#endif
#endif

__device__ __forceinline__ float fdot2(f16x2 a, f16x2 b, float c) {
#ifdef HAVE_FDOT2
  return __builtin_amdgcn_fdot2(a, b, c, false);
#else
  return c + (float)a[0] * (float)b[0] + (float)a[1] * (float)b[1];
#endif
}

union v8u {
  f16x8 v;
  f16x2 h[4];
};

__device__ __forceinline__ float tanh_fast(float s) {
  float e = __expf(2.0f * s);
  return 1.0f - 2.0f / (e + 1.0f);
}

// cross-lane float move via DPP; all lanes active required
template <int CTRL>
__device__ __forceinline__ float fdpp(float x) {
  int i = __builtin_bit_cast(int, x);
  i = __builtin_amdgcn_mov_dpp(i, CTRL, 0xf, 0xf, false);
  return __builtin_bit_cast(float, i);
}

// ---------------------------------------------------------------------------
// prep: W_su f32 [768][512] -> WzT f16 [h=512][k=512], WxT f16 [h=512][d=256]
// ---------------------------------------------------------------------------
__global__ __launch_bounds__(256) void prep_kernel(const float* __restrict__ Wsu,
                                                   f16* __restrict__ WzT,
                                                   f16* __restrict__ WxT) {
  int g = blockIdx.x * 256 + threadIdx.x;  // 0 .. 768*512-1
  int k = g >> 9;
  int h = g & 511;
  float v = Wsu[g];
  if (k < HID) WzT[h * HID + k] = (f16)v;
  else         WxT[h * IND + (k - HID)] = (f16)v;
}

// ---------------------------------------------------------------------------
// gemm1 v3 (MFMA, single-pass over x) -- proven ~30us in R12.
// ---------------------------------------------------------------------------
__global__ __launch_bounds__(256, 2) void gemm1_kernel(const float* __restrict__ x,
                                                       const f16* __restrict__ WxT,
                                                       const float* __restrict__ bsu,
                                                       f16* __restrict__ xw) {
  __shared__ __align__(16) char smem[65536];
  f16x8* Bbuf0 = (f16x8*)smem;            // 2048 f16x8 = 32 KB
  f16x8* Bbuf1 = (f16x8*)(smem + 32768);

  const int m0 = blockIdx.x * 64;
  const int tid = threadIdx.x;
  const int w = tid >> 6, l = tid & 63;
  const int r16 = l & 15;
  const int kg  = l >> 4;
  const int arow = m0 + w * 16 + r16;

  f32x4 acc[32];
#pragma unroll
  for (int nt = 0; nt < 32; ++nt) {
    float bv = bsu[nt * 16 + r16];
    acc[nt] = (f32x4){bv, bv, bv, bv};
  }

#pragma unroll
  for (int i = 0; i < 8; ++i) {
    int c = tid + 256 * i;
    int n = c >> 2;
    int g = c & 3;
    Bbuf0[g * 512 + n] = *(const f16x8*)&WxT[(size_t)n * IND + 0 + g * 8];
  }
  __syncthreads();

#pragma unroll
  for (int kb = 0; kb < 8; ++kb) {
    f16x8* Bc = (kb & 1) ? Bbuf1 : Bbuf0;
    f16x8* Bn = (kb & 1) ? Bbuf0 : Bbuf1;
    if (kb + 1 < 8) {
      const int k0n = (kb + 1) * 32;
#pragma unroll
      for (int i = 0; i < 8; ++i) {
        int c = tid + 256 * i;
        int n = c >> 2;
        int g = c & 3;
        Bn[g * 512 + n] = *(const f16x8*)&WxT[(size_t)n * IND + k0n + g * 8];
      }
    }
    const float4* ap = (const float4*)&x[(size_t)arow * IND + kb * 32 + kg * 8];
    float4 a0 = ap[0], a1 = ap[1];
    f16x8 afrag = {(f16)a0.x, (f16)a0.y, (f16)a0.z, (f16)a0.w,
                   (f16)a1.x, (f16)a1.y, (f16)a1.z, (f16)a1.w};
#pragma unroll
    for (int nt = 0; nt < 32; ++nt) {
      f16x8 bfrag = Bc[kg * 512 + nt * 16 + r16];
      acc[nt] = __builtin_amdgcn_mfma_f32_16x16x32_f16(afrag, bfrag, acc[nt], 0, 0, 0);
    }
    __syncthreads();
  }

  f16* Ot = (f16*)smem;
#pragma unroll
  for (int nt = 0; nt < 32; ++nt) {
#pragma unroll
    for (int r = 0; r < 4; ++r) {
      int row = w * 16 + kg * 4 + r;
      Ot[row * 512 + nt * 16 + r16] = (f16)acc[nt][r];
    }
  }
  __syncthreads();
#pragma unroll
  for (int i = 0; i < 16; ++i) {
    int c = tid + 256 * i;
    int row = c >> 6;
    int co = (c & 63) * 8;
    *(f16x8*)&xw[(size_t)(m0 + row) * HID + co] = *(const f16x8*)&Ot[row * 512 + co];
  }
}

// ---------------------------------------------------------------------------
// scan v7: 128 blocks (1 batch) x 256 threads (4 waves, 1 wave/SIMD,
// 512-VGPR cap). Lane map: w=tid>>6, l=tid&63; kc=l&7 (64-k chunk);
// hq=l>>3; thread owns 16 rows hb=w*128+hq*16 .. +15, k in [kc*64,+64).
// Rows 0..11 register-resident (384 VGPR); rows 12..15 from LDS wl
// (static, written once). z-reads: 8 swizzled broadcast b128.
// Reduce over kc fully in-register: 3-stage DPP pack-reduce
// (xor7 0x141 sel b2, xor1 0xB1 sel b0, xor2 0x4E sel b1) -- 16 accs -> 2.
// Lane ends with rows myh, myh+1 (myh = hb + 8*b2+4*b0+2*b1).
// ONE barrier per step; zsh double-buffered; zero divergence.
// ---------------------------------------------------------------------------
__global__ __launch_bounds__(256, 1) void scan_kernel(
    const f16* __restrict__ WzT, const f16* __restrict__ xw,
    const float* __restrict__ carry, const float* __restrict__ Wout,
    const float* __restrict__ bout, float* __restrict__ outp) {
  __shared__ __align__(16) f16 zsh[2][512];        // 2 KB double-buffered z
  __shared__ __align__(16) f16x8 wl[4][8][256];    // 128 KB rows 12..15
  __shared__ float red[512];                       // 2 KB epilogue

  const int b_ = blockIdx.x;
  const int tid = threadIdx.x;
  const int w = tid >> 6, l = tid & 63;
  const int kc = l & 7;
  const int hq = l >> 3;
  const int hb = w * 128 + hq * 16;

  // rows hb..hb+11 -> registers (384 VGPRs), slice-permuted by (s^kc)
  f16x2 wreg[12][32];
#pragma unroll
  for (int r = 0; r < 12; ++r) {
#pragma unroll
    for (int s = 0; s < 8; ++s) {
      v8u v;
      v.v = *(const f16x8*)&WzT[(size_t)(hb + r) * HID + kc * 64 + ((s ^ kc) & 7) * 8];
#pragma unroll
      for (int p = 0; p < 4; ++p) wreg[r][s * 4 + p] = v.h[p];
    }
  }
  // opacity pin: prevent remat/sinking
#pragma unroll
  for (int r = 0; r < 12; ++r) {
#pragma unroll
    for (int s = 0; s < 32; ++s) {
      unsigned u = __builtin_bit_cast(unsigned, wreg[r][s]);
      asm volatile("" : "+v"(u));
      wreg[r][s] = __builtin_bit_cast(f16x2, u);
    }
  }
  // rows hb+12..hb+15 -> LDS in consumption order (static across steps)
#pragma unroll
  for (int j = 0; j < 4; ++j)
#pragma unroll
    for (int s = 0; s < 8; ++s)
      wl[j][s][tid] = *(const f16x8*)&WzT[(size_t)(hb + 12 + j) * HID + kc * 64 + ((s ^ kc) & 7) * 8];

  // z^0 from carry: 2 values per thread
  {
    float2 c2 = *(const float2*)&carry[b_ * HID + 2 * tid];
    *(f16x2*)&zsh[0][2 * tid] = (f16x2){(f16)c2.x, (f16)c2.y};
  }

  const int b0 = kc & 1, b1 = (kc >> 1) & 1, b2 = (kc >> 2) & 1;
  const int myh = hb + (b2 << 3) + (b0 << 2) + (b1 << 1);  // even

  f16x2 xwv = *(const f16x2*)&xw[(size_t)b_ * SEQ * HID + myh];
  float xc0 = (float)xwv[0], xc1 = (float)xwv[1];

  __syncthreads();

  float zl0 = 0.f, zl1 = 0.f;
  for (int t = 0; t < SEQ; ++t) {
    const int p = t & 1;
    int tn = (t + 1 < SEQ) ? t + 1 : t;
    f16x2 xn = *(const f16x2*)&xw[((size_t)b_ * SEQ + tn) * HID + myh];

    const f16* zb = &zsh[p][kc * 64];
    float a[16];
#pragma unroll
    for (int r = 0; r < 16; ++r) a[r] = 0.f;
#pragma unroll
    for (int s = 0; s < 8; ++s) {
      v8u zc, w12, w13, w14, w15;
      zc.v  = *(const f16x8*)&zb[((s ^ kc) & 7) * 8];  // broadcast, bank-spread
      w12.v = wl[0][s][tid];
      w13.v = wl[1][s][tid];
      w14.v = wl[2][s][tid];
      w15.v = wl[3][s][tid];
#pragma unroll
      for (int q = 0; q < 4; ++q) {
        f16x2 zp = zc.h[q];
        int pi = s * 4 + q;
        a[0]  = fdot2(zp, wreg[0][pi],  a[0]);
        a[1]  = fdot2(zp, wreg[1][pi],  a[1]);
        a[2]  = fdot2(zp, wreg[2][pi],  a[2]);
        a[3]  = fdot2(zp, wreg[3][pi],  a[3]);
        a[4]  = fdot2(zp, wreg[4][pi],  a[4]);
        a[5]  = fdot2(zp, wreg[5][pi],  a[5]);
        a[6]  = fdot2(zp, wreg[6][pi],  a[6]);
        a[7]  = fdot2(zp, wreg[7][pi],  a[7]);
        a[8]  = fdot2(zp, wreg[8][pi],  a[8]);
        a[9]  = fdot2(zp, wreg[9][pi],  a[9]);
        a[10] = fdot2(zp, wreg[10][pi], a[10]);
        a[11] = fdot2(zp, wreg[11][pi], a[11]);
        a[12] = fdot2(zp, w12.h[q], a[12]);
        a[13] = fdot2(zp, w13.h[q], a[13]);
        a[14] = fdot2(zp, w14.h[q], a[14]);
        a[15] = fdot2(zp, w15.h[q], a[15]);
      }
    }

    // ---- 3-stage in-register pack-reduce over kc ----
    // stage 1: xor7 (0x141), select b2: pairs (a[j], a[j+8])
    float u[8];
#pragma unroll
    for (int j = 0; j < 8; ++j) {
      float keep = b2 ? a[j + 8] : a[j];
      float send = b2 ? a[j] : a[j + 8];
      u[j] = keep + fdpp<0x141>(send);
    }
    // stage 2: xor1 (0xB1), select b0: pairs (u[j], u[j+4])
    float v[4];
#pragma unroll
    for (int j = 0; j < 4; ++j) {
      float keep = b0 ? u[j + 4] : u[j];
      float send = b0 ? u[j] : u[j + 4];
      v[j] = keep + fdpp<0xB1>(send);
    }
    // stage 3: xor2 (0x4E), select b1: pairs (v[j], v[j+2])
    float t0 = (b1 ? v[2] : v[0]) + fdpp<0x4E>(b1 ? v[0] : v[2]);
    float t1 = (b1 ? v[3] : v[1]) + fdpp<0x4E>(b1 ? v[1] : v[3]);
    // lane holds full sums for rows myh, myh+1

    float z0 = tanh_fast(t0 + xc0);
    float z1 = tanh_fast(t1 + xc1);
    zl0 = z0; zl1 = z1;
    *(f16x2*)&zsh[p ^ 1][myh] = (f16x2){(f16)z0, (f16)z1};
    __syncthreads();
    xc0 = (float)xn[0];
    xc1 = (float)xn[1];
  }

  // outputs: z_last (f32, exact from registers) + out[b] GEMV
  *(float2*)&outp[BATCH + (size_t)b_ * HID + myh] = (float2){zl0, zl1};
  red[myh]     = zl0 * Wout[myh];
  red[myh + 1] = zl1 * Wout[myh + 1];
  __syncthreads();
  if (tid < 64) {
    float s2 = 0.f;
#pragma unroll
    for (int i = 0; i < 8; ++i) s2 += red[tid + 64 * i];
    red[tid] = s2;
  }
  __syncthreads();
  if (tid == 0) {
    float s3 = 0.f;
    for (int i = 0; i < 64; ++i) s3 += red[i];
    outp[b_] = s3 + bout[0];
  }
}

// ---------------------------------------------------------------------------
extern "C" void kernel_launch(void* const* d_in, const int* in_sizes, int n_in,
                              void* d_out, int out_size, void* d_ws, size_t ws_size,
                              hipStream_t stream) {
  const float* x     = (const float*)d_in[0];
  const float* carry = (const float*)d_in[1];
  const float* Wsu   = (const float*)d_in[2];
  const float* bsu   = (const float*)d_in[3];
  const float* Wout  = (const float*)d_in[4];
  const float* bout  = (const float*)d_in[5];
  float* outp = (float*)d_out;

  char* ws = (char*)d_ws;
  f16* WzT = (f16*)(ws);                        // 512 KB
  f16* WxT = (f16*)(ws + 512 * 1024);           // 256 KB
  f16* xw  = (f16*)(ws + 768 * 1024);           // 128 MB (131072*512*2B)

  prep_kernel<<<dim3((768 * 512) / 256), 256, 0, stream>>>(Wsu, WzT, WxT);
  gemm1_kernel<<<dim3(BATCH * SEQ / 64), 256, 0, stream>>>(x, WxT, bsu, xw);
  scan_kernel<<<dim3(BATCH), 256, 0, stream>>>(WzT, xw, carry, Wout, bout, outp);
}

// Round 14
// 1653.430 us; speedup vs baseline: 1.4573x; 1.4573x over previous
//
#include <hip/hip_runtime.h>
#include <hip/hip_bf16.h>

typedef _Float16 f16;
typedef _Float16 f16x2 __attribute__((ext_vector_type(2)));
typedef _Float16 f16x4 __attribute__((ext_vector_type(4)));
typedef _Float16 f16x8 __attribute__((ext_vector_type(8)));
typedef float f32x4 __attribute__((ext_vector_type(4)));

#define BATCH 128
#define SEQ   1024
#define IND   256
#define HID   512

#if defined(__has_builtin)
#if __has_builtin(__builtin_amdgcn_fdot2)
#define HAVE_FDOT2 1
#endif
#endif

__device__ __forceinline__ float fdot2(f16x2 a, f16x2 b, float c) {
#ifdef HAVE_FDOT2
  return __builtin_amdgcn_fdot2(a, b, c, false);
#else
  return c + (float)a[0] * (float)b[0] + (float)a[1] * (float)b[1];
#endif
}

union v8u {
  f16x8 v;
  f16x2 h[4];
};

__device__ __forceinline__ float tanh_fast(float s) {
  float e = __expf(2.0f * s);
  return 1.0f - 2.0f / (e + 1.0f);
}

// cross-lane float move via DPP; all lanes active required
template <int CTRL>
__device__ __forceinline__ float fdpp(float x) {
  int i = __builtin_bit_cast(int, x);
  i = __builtin_amdgcn_mov_dpp(i, CTRL, 0xf, 0xf, false);
  return __builtin_bit_cast(float, i);
}

// ---------------------------------------------------------------------------
// prep: W_su f32 [768][512] -> WzT f16 [h=512][k=512], WxT f16 [h=512][d=256]
// ---------------------------------------------------------------------------
__global__ __launch_bounds__(256) void prep_kernel(const float* __restrict__ Wsu,
                                                   f16* __restrict__ WzT,
                                                   f16* __restrict__ WxT) {
  int g = blockIdx.x * 256 + threadIdx.x;  // 0 .. 768*512-1
  int k = g >> 9;
  int h = g & 511;
  float v = Wsu[g];
  if (k < HID) WzT[h * HID + k] = (f16)v;
  else         WxT[h * IND + (k - HID)] = (f16)v;
}

// ---------------------------------------------------------------------------
// gemm1 v3 (MFMA, single-pass over x) -- proven ~30us in R12.
// ---------------------------------------------------------------------------
__global__ __launch_bounds__(256, 2) void gemm1_kernel(const float* __restrict__ x,
                                                       const f16* __restrict__ WxT,
                                                       const float* __restrict__ bsu,
                                                       f16* __restrict__ xw) {
  __shared__ __align__(16) char smem[65536];
  f16x8* Bbuf0 = (f16x8*)smem;            // 2048 f16x8 = 32 KB
  f16x8* Bbuf1 = (f16x8*)(smem + 32768);

  const int m0 = blockIdx.x * 64;
  const int tid = threadIdx.x;
  const int w = tid >> 6, l = tid & 63;
  const int r16 = l & 15;
  const int kg  = l >> 4;
  const int arow = m0 + w * 16 + r16;

  f32x4 acc[32];
#pragma unroll
  for (int nt = 0; nt < 32; ++nt) {
    float bv = bsu[nt * 16 + r16];
    acc[nt] = (f32x4){bv, bv, bv, bv};
  }

#pragma unroll
  for (int i = 0; i < 8; ++i) {
    int c = tid + 256 * i;
    int n = c >> 2;
    int g = c & 3;
    Bbuf0[g * 512 + n] = *(const f16x8*)&WxT[(size_t)n * IND + 0 + g * 8];
  }
  __syncthreads();

#pragma unroll
  for (int kb = 0; kb < 8; ++kb) {
    f16x8* Bc = (kb & 1) ? Bbuf1 : Bbuf0;
    f16x8* Bn = (kb & 1) ? Bbuf0 : Bbuf1;
    if (kb + 1 < 8) {
      const int k0n = (kb + 1) * 32;
#pragma unroll
      for (int i = 0; i < 8; ++i) {
        int c = tid + 256 * i;
        int n = c >> 2;
        int g = c & 3;
        Bn[g * 512 + n] = *(const f16x8*)&WxT[(size_t)n * IND + k0n + g * 8];
      }
    }
    const float4* ap = (const float4*)&x[(size_t)arow * IND + kb * 32 + kg * 8];
    float4 a0 = ap[0], a1 = ap[1];
    f16x8 afrag = {(f16)a0.x, (f16)a0.y, (f16)a0.z, (f16)a0.w,
                   (f16)a1.x, (f16)a1.y, (f16)a1.z, (f16)a1.w};
#pragma unroll
    for (int nt = 0; nt < 32; ++nt) {
      f16x8 bfrag = Bc[kg * 512 + nt * 16 + r16];
      acc[nt] = __builtin_amdgcn_mfma_f32_16x16x32_f16(afrag, bfrag, acc[nt], 0, 0, 0);
    }
    __syncthreads();
  }

  f16* Ot = (f16*)smem;
#pragma unroll
  for (int nt = 0; nt < 32; ++nt) {
#pragma unroll
    for (int r = 0; r < 4; ++r) {
      int row = w * 16 + kg * 4 + r;
      Ot[row * 512 + nt * 16 + r16] = (f16)acc[nt][r];
    }
  }
  __syncthreads();
#pragma unroll
  for (int i = 0; i < 16; ++i) {
    int c = tid + 256 * i;
    int row = c >> 6;
    int co = (c & 63) * 8;
    *(f16x8*)&xw[(size_t)(m0 + row) * HID + co] = *(const f16x8*)&Ot[row * 512 + co];
  }
}

// ---------------------------------------------------------------------------
// scan v8: 128 blocks (1 batch) x 512 threads (8 waves, 2/SIMD, proven
// occupancy optimum). NEW GEOMETRY: k-chunk 32 f16.
// Lane map: w=tid>>6, l=tid&63; kq=l&15 (k in [kq*32,+32)); hq=l>>4;
// thread owns 16 rows hb=w*64+hq*16 .. +15.
// Rows 0..12 register-resident (208 f16x2); rows 13..15 from LDS (12 b128).
// z-reads: 4 b128 per thread (was 8), slice order s'=(s+(kq>>1))&3 ->
// 2-way bank aliasing only (free). Weights pre-permuted to match.
// Reduce over kq fully in-register, 4-stage DPP pack-reduce:
//   xor8 = row_ror:8 (0x128) sel b3 -> xor7 (0x141) sel b2 ->
//   xor1 (0xB1) sel b0 -> xor2 (0x4E) sel b1.  16 accs -> 1.
// Lane ends with row myh = hb + 8*b3+4*b2+2*b0+b1 (bijective).
// ONE barrier/step, zsh double-buffered, zero divergence.
// ---------------------------------------------------------------------------
__global__ __launch_bounds__(512, 2) void scan_kernel(
    const f16* __restrict__ WzT, const f16* __restrict__ xw,
    const float* __restrict__ carry, const float* __restrict__ Wout,
    const float* __restrict__ bout, float* __restrict__ outp) {
  __shared__ __align__(16) f16 zsh[2][512];        // 2 KB double-buffered z
  __shared__ __align__(16) f16x8 wl[12][512];      // 96 KB rows 13..15
  __shared__ float red[512];                       // 2 KB epilogue

  const int b_ = blockIdx.x;
  const int tid = threadIdx.x;
  const int w = tid >> 6, l = tid & 63;
  const int kq = l & 15;
  const int hq = l >> 4;
  const int hb = w * 64 + hq * 16;

  // slice permutation (bank spread): s' = (s + (kq>>1)) & 3
  const int rot = (kq >> 1) & 3;

  // rows hb..hb+12 -> registers (208 f16x2), slice-permuted
  f16x2 wreg[13][16];
#pragma unroll
  for (int r = 0; r < 13; ++r) {
#pragma unroll
    for (int s = 0; s < 4; ++s) {
      int sp = (s + rot) & 3;
      v8u v;
      v.v = *(const f16x8*)&WzT[(size_t)(hb + r) * HID + kq * 32 + sp * 8];
#pragma unroll
      for (int p = 0; p < 4; ++p) wreg[r][s * 4 + p] = v.h[p];
    }
  }
  // opacity pin: prevent remat/sinking of register-resident rows
#pragma unroll
  for (int r = 0; r < 13; ++r) {
#pragma unroll
    for (int s = 0; s < 16; ++s) {
      unsigned u = __builtin_bit_cast(unsigned, wreg[r][s]);
      asm volatile("" : "+v"(u));
      wreg[r][s] = __builtin_bit_cast(f16x2, u);
    }
  }
  // rows hb+13..hb+15 -> LDS in consumption order (written once)
#pragma unroll
  for (int r = 0; r < 3; ++r)
#pragma unroll
    for (int s = 0; s < 4; ++s) {
      int sp = (s + rot) & 3;
      wl[r * 4 + s][tid] =
          *(const f16x8*)&WzT[(size_t)(hb + 13 + r) * HID + kq * 32 + sp * 8];
    }

  // z^0 from carry, plain layout
  zsh[0][tid] = (f16)carry[b_ * HID + tid];

  const int b0 = l & 1, b1 = (l >> 1) & 1, b2 = (l >> 2) & 1, b3 = (l >> 3) & 1;
  const int myh = hb + (b3 << 3) + (b2 << 2) + (b0 << 1) + b1;

  float xw_cur = (float)xw[(size_t)b_ * SEQ * HID + myh];

  __syncthreads();

  float zlast = 0.f;
  for (int t = 0; t < SEQ; ++t) {
    const int p = t & 1;
    int tn = (t + 1 < SEQ) ? t + 1 : t;
    f16 xn = xw[((size_t)b_ * SEQ + tn) * HID + myh];

    const f16* zb = &zsh[p][kq * 32];
    float a[16];
#pragma unroll
    for (int r = 0; r < 16; ++r) a[r] = 0.f;
#pragma unroll
    for (int s = 0; s < 4; ++s) {
      int sp = (s + rot) & 3;
      v8u zc, w13, w14, w15;
      zc.v  = *(const f16x8*)&zb[sp * 8];   // 2-way bank alias only
      w13.v = wl[s][tid];
      w14.v = wl[4 + s][tid];
      w15.v = wl[8 + s][tid];
#pragma unroll
      for (int q = 0; q < 4; ++q) {
        f16x2 zp = zc.h[q];
        int pi = s * 4 + q;
        a[0]  = fdot2(zp, wreg[0][pi],  a[0]);
        a[1]  = fdot2(zp, wreg[1][pi],  a[1]);
        a[2]  = fdot2(zp, wreg[2][pi],  a[2]);
        a[3]  = fdot2(zp, wreg[3][pi],  a[3]);
        a[4]  = fdot2(zp, wreg[4][pi],  a[4]);
        a[5]  = fdot2(zp, wreg[5][pi],  a[5]);
        a[6]  = fdot2(zp, wreg[6][pi],  a[6]);
        a[7]  = fdot2(zp, wreg[7][pi],  a[7]);
        a[8]  = fdot2(zp, wreg[8][pi],  a[8]);
        a[9]  = fdot2(zp, wreg[9][pi],  a[9]);
        a[10] = fdot2(zp, wreg[10][pi], a[10]);
        a[11] = fdot2(zp, wreg[11][pi], a[11]);
        a[12] = fdot2(zp, wreg[12][pi], a[12]);
        a[13] = fdot2(zp, w13.h[q], a[13]);
        a[14] = fdot2(zp, w14.h[q], a[14]);
        a[15] = fdot2(zp, w15.h[q], a[15]);
      }
    }

    // ---- 4-stage in-register pack-reduce over kq (lane bits 0..3) ----
    // stage 1: xor8 (row_ror:8 = 0x128), select b3
    float u[8];
#pragma unroll
    for (int j = 0; j < 8; ++j) {
      float keep = b3 ? a[j + 8] : a[j];
      float send = b3 ? a[j] : a[j + 8];
      u[j] = keep + fdpp<0x128>(send);
    }
    // stage 2: xor7 (row_half_mirror = 0x141), select b2
    float v[4];
#pragma unroll
    for (int j = 0; j < 4; ++j) {
      float keep = b2 ? u[j + 4] : u[j];
      float send = b2 ? u[j] : u[j + 4];
      v[j] = keep + fdpp<0x141>(send);
    }
    // stage 3: xor1 (quad_perm 0xB1), select b0
    float t2[2];
#pragma unroll
    for (int j = 0; j < 2; ++j) {
      float keep = b0 ? v[j + 2] : v[j];
      float send = b0 ? v[j] : v[j + 2];
      t2[j] = keep + fdpp<0xB1>(send);
    }
    // stage 4: xor2 (quad_perm 0x4E), select b1
    float tot = (b1 ? t2[1] : t2[0]) + fdpp<0x4E>(b1 ? t2[0] : t2[1]);
    // lane holds full sum for row myh

    float z = tanh_fast(tot + xw_cur);
    zlast = z;
    zsh[p ^ 1][myh] = (f16)z;
    __syncthreads();
    xw_cur = (float)xn;
  }

  // outputs: z_last (f32, exact from register) + out[b] GEMV
  outp[BATCH + (size_t)b_ * HID + myh] = zlast;
  red[myh] = zlast * Wout[myh];
  __syncthreads();
  if (tid < 64) {
    float s2 = 0.f;
#pragma unroll
    for (int i = 0; i < 8; ++i) s2 += red[tid + 64 * i];
    red[tid] = s2;
  }
  __syncthreads();
  if (tid == 0) {
    float s3 = 0.f;
    for (int i = 0; i < 64; ++i) s3 += red[i];
    outp[b_] = s3 + bout[0];
  }
}

// ---------------------------------------------------------------------------
extern "C" void kernel_launch(void* const* d_in, const int* in_sizes, int n_in,
                              void* d_out, int out_size, void* d_ws, size_t ws_size,
                              hipStream_t stream) {
  const float* x     = (const float*)d_in[0];
  const float* carry = (const float*)d_in[1];
  const float* Wsu   = (const float*)d_in[2];
  const float* bsu   = (const float*)d_in[3];
  const float* Wout  = (const float*)d_in[4];
  const float* bout  = (const float*)d_in[5];
  float* outp = (float*)d_out;

  char* ws = (char*)d_ws;
  f16* WzT = (f16*)(ws);                        // 512 KB
  f16* WxT = (f16*)(ws + 512 * 1024);           // 256 KB
  f16* xw  = (f16*)(ws + 768 * 1024);           // 128 MB (131072*512*2B)

  prep_kernel<<<dim3((768 * 512) / 256), 256, 0, stream>>>(Wsu, WzT, WxT);
  gemm1_kernel<<<dim3(BATCH * SEQ / 64), 256, 0, stream>>>(x, WxT, bsu, xw);
  scan_kernel<<<dim3(BATCH), 512, 0, stream>>>(WzT, xw, carry, Wout, bout, outp);
}

// Round 16
// 1442.411 us; speedup vs baseline: 1.6705x; 1.1463x over previous
//
#include <hip/hip_runtime.h>
#include <hip/hip_bf16.h>

typedef _Float16 f16;
typedef _Float16 f16x2 __attribute__((ext_vector_type(2)));
typedef _Float16 f16x4 __attribute__((ext_vector_type(4)));
typedef _Float16 f16x8 __attribute__((ext_vector_type(8)));
typedef float f32x4 __attribute__((ext_vector_type(4)));

#define BATCH 128
#define SEQ   1024
#define IND   256
#define HID   512

#if defined(__has_builtin)
#if __has_builtin(__builtin_amdgcn_fdot2)
#define HAVE_FDOT2 1
#endif
#endif

__device__ __forceinline__ float fdot2(f16x2 a, f16x2 b, float c) {
#ifdef HAVE_FDOT2
  return __builtin_amdgcn_fdot2(a, b, c, false);
#else
  return c + (float)a[0] * (float)b[0] + (float)a[1] * (float)b[1];
#endif
}

union v8u {
  f16x8 v;
  f16x2 h[4];
};

__device__ __forceinline__ float tanh_fast(float s) {
  float e = __expf(2.0f * s);
  return 1.0f - 2.0f / (e + 1.0f);
}

// cross-lane float move via DPP; all lanes active required
template <int CTRL>
__device__ __forceinline__ float fdpp(float x) {
  int i = __builtin_bit_cast(int, x);
  i = __builtin_amdgcn_mov_dpp(i, CTRL, 0xf, 0xf, false);
  return __builtin_bit_cast(float, i);
}

// ---------------------------------------------------------------------------
// prep: W_su f32 [768][512] -> WzT f16 [h=512][k=512], WxT f16 [h=512][d=256]
// ---------------------------------------------------------------------------
__global__ __launch_bounds__(256) void prep_kernel(const float* __restrict__ Wsu,
                                                   f16* __restrict__ WzT,
                                                   f16* __restrict__ WxT) {
  int g = blockIdx.x * 256 + threadIdx.x;  // 0 .. 768*512-1
  int k = g >> 9;
  int h = g & 511;
  float v = Wsu[g];
  if (k < HID) WzT[h * HID + k] = (f16)v;
  else         WxT[h * IND + (k - HID)] = (f16)v;
}

// ---------------------------------------------------------------------------
// gemm1 v3 (MFMA, single-pass over x): xw[m][n] = sum_k x[m][k]*WxT[n][k]+bsu
// Grid (2048,1): block = 64 m-rows x ALL 512 n. 256 threads (4 waves).
// x read ONCE from HBM; WxT K-slice double-buffered in LDS; epilogue via
// LDS transpose -> coalesced f16x8 stores. Proven ~30us (R12).
// ---------------------------------------------------------------------------
__global__ __launch_bounds__(256, 2) void gemm1_kernel(const float* __restrict__ x,
                                                       const f16* __restrict__ WxT,
                                                       const float* __restrict__ bsu,
                                                       f16* __restrict__ xw) {
  __shared__ __align__(16) char smem[65536];
  f16x8* Bbuf0 = (f16x8*)smem;            // 2048 f16x8 = 32 KB
  f16x8* Bbuf1 = (f16x8*)(smem + 32768);

  const int m0 = blockIdx.x * 64;
  const int tid = threadIdx.x;
  const int w = tid >> 6, l = tid & 63;
  const int r16 = l & 15;
  const int kg  = l >> 4;
  const int arow = m0 + w * 16 + r16;

  f32x4 acc[32];
#pragma unroll
  for (int nt = 0; nt < 32; ++nt) {
    float bv = bsu[nt * 16 + r16];
    acc[nt] = (f32x4){bv, bv, bv, bv};
  }

#pragma unroll
  for (int i = 0; i < 8; ++i) {
    int c = tid + 256 * i;
    int n = c >> 2;
    int g = c & 3;
    Bbuf0[g * 512 + n] = *(const f16x8*)&WxT[(size_t)n * IND + 0 + g * 8];
  }
  __syncthreads();

#pragma unroll
  for (int kb = 0; kb < 8; ++kb) {
    f16x8* Bc = (kb & 1) ? Bbuf1 : Bbuf0;
    f16x8* Bn = (kb & 1) ? Bbuf0 : Bbuf1;
    if (kb + 1 < 8) {
      const int k0n = (kb + 1) * 32;
#pragma unroll
      for (int i = 0; i < 8; ++i) {
        int c = tid + 256 * i;
        int n = c >> 2;
        int g = c & 3;
        Bn[g * 512 + n] = *(const f16x8*)&WxT[(size_t)n * IND + k0n + g * 8];
      }
    }
    const float4* ap = (const float4*)&x[(size_t)arow * IND + kb * 32 + kg * 8];
    float4 a0 = ap[0], a1 = ap[1];
    f16x8 afrag = {(f16)a0.x, (f16)a0.y, (f16)a0.z, (f16)a0.w,
                   (f16)a1.x, (f16)a1.y, (f16)a1.z, (f16)a1.w};
#pragma unroll
    for (int nt = 0; nt < 32; ++nt) {
      f16x8 bfrag = Bc[kg * 512 + nt * 16 + r16];
      acc[nt] = __builtin_amdgcn_mfma_f32_16x16x32_f16(afrag, bfrag, acc[nt], 0, 0, 0);
    }
    __syncthreads();
  }

  f16* Ot = (f16*)smem;
#pragma unroll
  for (int nt = 0; nt < 32; ++nt) {
#pragma unroll
    for (int r = 0; r < 4; ++r) {
      int row = w * 16 + kg * 4 + r;
      Ot[row * 512 + nt * 16 + r16] = (f16)acc[nt][r];
    }
  }
  __syncthreads();
#pragma unroll
  for (int i = 0; i < 16; ++i) {
    int c = tid + 256 * i;
    int row = c >> 6;
    int co = (c & 63) * 8;
    *(f16x8*)&xw[(size_t)(m0 + row) * HID + co] = *(const f16x8*)&Ot[row * 512 + co];
  }
}

// ---------------------------------------------------------------------------
// scan v5 (R9/R12, proven 1410us): 128 blocks x 512 threads (8 waves,
// 2/SIMD -- measured optimum of the 4/8/16-wave sweep).
// Lane map: w=tid>>6, l=tid&63; kc=l&7 (64-k chunk); hq=l>>3 (row octet);
// thread owns rows hbase=w*64+hq*8 .. +7, k in [kc*64, kc*64+64).
// Rows 0..5 register-resident (192 f16x2 -- measured optimum of the
// 5/6/7/12/13-row residency sweep); rows 6,7 streamed from LDS wl6/wl7
// (conflict-free contiguous b128).
// z-reads: 8 swizzled broadcast b128. Cross-chunk reduce in-register:
// xor7 (dpp 0x141) -> xor1 (0xB1) -> xor2 (0x4E), all HW-validated.
// ONE barrier per step; zsh double-buffered; zero divergence.
// ---------------------------------------------------------------------------
__global__ __launch_bounds__(512, 2) void scan_kernel(
    const f16* __restrict__ WzT, const f16* __restrict__ xw,
    const float* __restrict__ carry, const float* __restrict__ Wout,
    const float* __restrict__ bout, float* __restrict__ outp) {
  __shared__ __align__(16) f16 zsh[2][512];        // 2 KB double-buffered z
  __shared__ __align__(16) f16x8 wl6[8][512];      // 64 KB row-6 weights
  __shared__ __align__(16) f16x8 wl7[8][512];      // 64 KB row-7 weights
  __shared__ float red[512];                       // 2 KB epilogue

  const int b_ = blockIdx.x;
  const int tid = threadIdx.x;
  const int w = tid >> 6, l = tid & 63;
  const int kc = l & 7;
  const int hq = l >> 3;
  const int hbase = w * 64 + hq * 8;

  // rows hbase..hbase+5 -> registers, slice-permuted by (s^kc)
  f16x2 wreg[6][32];
#pragma unroll
  for (int r = 0; r < 6; ++r) {
#pragma unroll
    for (int s = 0; s < 8; ++s) {
      v8u v;
      v.v = *(const f16x8*)&WzT[(hbase + r) * HID + kc * 64 + ((s ^ kc) & 7) * 8];
#pragma unroll
      for (int p = 0; p < 4; ++p) wreg[r][s * 4 + p] = v.h[p];
    }
  }
  // opacity pin: prevent remat/sinking
#pragma unroll
  for (int r = 0; r < 6; ++r) {
#pragma unroll
    for (int s = 0; s < 32; ++s) {
      unsigned u = __builtin_bit_cast(unsigned, wreg[r][s]);
      asm volatile("" : "+v"(u));
      wreg[r][s] = __builtin_bit_cast(f16x2, u);
    }
  }
  // rows hbase+6, hbase+7 -> LDS in consumption order
#pragma unroll
  for (int s = 0; s < 8; ++s) {
    wl6[s][tid] = *(const f16x8*)&WzT[(hbase + 6) * HID + kc * 64 + ((s ^ kc) & 7) * 8];
    wl7[s][tid] = *(const f16x8*)&WzT[(hbase + 7) * HID + kc * 64 + ((s ^ kc) & 7) * 8];
  }

  // z^0 from carry, plain layout
  zsh[0][tid] = (f16)carry[b_ * HID + tid];

  // output row after pack-reduce: hbase + 4*b2 + 2*b0 + b1
  const int b0 = l & 1, b1 = (l >> 1) & 1, b2 = (l >> 2) & 1;
  const int myh = hbase + (b2 << 2) + (b0 << 1) + b1;

  float xw_cur = (float)xw[(size_t)b_ * SEQ * HID + myh];

  __syncthreads();

  float zlast = 0.f;
  for (int t = 0; t < SEQ; ++t) {
    const int p = t & 1;
    int tn = (t + 1 < SEQ) ? t + 1 : t;
    float xw_nxt = (float)xw[((size_t)b_ * SEQ + tn) * HID + myh];

    const f16* zb = &zsh[p][kc * 64];
    float a0 = 0.f, a1 = 0.f, a2 = 0.f, a3 = 0.f;
    float a4 = 0.f, a5 = 0.f, a6 = 0.f, a7 = 0.f;
#pragma unroll
    for (int s = 0; s < 8; ++s) {
      v8u zc, w6, w7;
      zc.v = *(const f16x8*)&zb[((s ^ kc) & 7) * 8];  // broadcast, bank-spread
      w6.v = wl6[s][tid];
      w7.v = wl7[s][tid];
#pragma unroll
      for (int q4 = 0; q4 < 4; ++q4) {
        f16x2 zp = zc.h[q4];
        int pi = s * 4 + q4;
        a0 = fdot2(zp, wreg[0][pi], a0);
        a1 = fdot2(zp, wreg[1][pi], a1);
        a2 = fdot2(zp, wreg[2][pi], a2);
        a3 = fdot2(zp, wreg[3][pi], a3);
        a4 = fdot2(zp, wreg[4][pi], a4);
        a5 = fdot2(zp, wreg[5][pi], a5);
        a6 = fdot2(zp, w6.h[q4], a6);
        a7 = fdot2(zp, w7.h[q4], a7);
      }
    }

    // ---- in-register pack-reduce over kc (lane bits 0,1,2) ----
    float n0_ = b2 ? a4 : a0, s0_ = b2 ? a0 : a4;
    float n1_ = b2 ? a5 : a1, s1_ = b2 ? a1 : a5;
    float n2_ = b2 ? a6 : a2, s2_ = b2 ? a2 : a6;
    float n3_ = b2 ? a7 : a3, s3_ = b2 ? a3 : a7;
    n0_ += fdpp<0x141>(s0_);
    n1_ += fdpp<0x141>(s1_);
    n2_ += fdpp<0x141>(s2_);
    n3_ += fdpp<0x141>(s3_);
    float m0_ = b0 ? n2_ : n0_, t0_ = b0 ? n0_ : n2_;
    float m1_ = b0 ? n3_ : n1_, t1_ = b0 ? n1_ : n3_;
    m0_ += fdpp<0xB1>(t0_);
    m1_ += fdpp<0xB1>(t1_);
    float f0_ = b1 ? m1_ : m0_, g0_ = b1 ? m0_ : m1_;
    float tot = f0_ + fdpp<0x4E>(g0_);

    float z = tanh_fast(tot + xw_cur);
    zlast = z;
    zsh[p ^ 1][myh] = (f16)z;
    __syncthreads();
    xw_cur = xw_nxt;
  }

  // outputs: z_last (f32, exact from register) + out[b] GEMV
  outp[BATCH + (size_t)b_ * HID + myh] = zlast;
  red[myh] = zlast * Wout[myh];
  __syncthreads();
  if (tid < 64) {
    float s2 = 0.f;
#pragma unroll
    for (int i = 0; i < 8; ++i) s2 += red[tid + 64 * i];
    red[tid] = s2;
  }
  __syncthreads();
  if (tid == 0) {
    float s3 = 0.f;
    for (int i = 0; i < 64; ++i) s3 += red[i];
    outp[b_] = s3 + bout[0];
  }
}

// ---------------------------------------------------------------------------
extern "C" void kernel_launch(void* const* d_in, const int* in_sizes, int n_in,
                              void* d_out, int out_size, void* d_ws, size_t ws_size,
                              hipStream_t stream) {
  const float* x     = (const float*)d_in[0];
  const float* carry = (const float*)d_in[1];
  const float* Wsu   = (const float*)d_in[2];
  const float* bsu   = (const float*)d_in[3];
  const float* Wout  = (const float*)d_in[4];
  const float* bout  = (const float*)d_in[5];
  float* outp = (float*)d_out;

  char* ws = (char*)d_ws;
  f16* WzT = (f16*)(ws);                        // 512 KB
  f16* WxT = (f16*)(ws + 512 * 1024);           // 256 KB
  f16* xw  = (f16*)(ws + 768 * 1024);           // 128 MB (131072*512*2B)

  prep_kernel<<<dim3((768 * 512) / 256), 256, 0, stream>>>(Wsu, WzT, WxT);
  gemm1_kernel<<<dim3(BATCH * SEQ / 64), 256, 0, stream>>>(x, WxT, bsu, xw);
  scan_kernel<<<dim3(BATCH), 512, 0, stream>>>(WzT, xw, carry, Wout, bout, outp);
}